// Round 1
// 426.353 us; speedup vs baseline: 1.1699x; 1.1699x over previous
//
#include <hip/hip_runtime.h>
#include <hip/hip_bf16.h>
#include <cstdint>
#include <cstddef>

// ---------------------------------------------------------------------------
// SelfAttention: qkv = x@Wqkv^T ; P' = exp(Q@K^T*0.125) ; l = rowsum(P') ;
// O' = P'@V ; y = (O'@Wout^T)/l + b.  bf16 MFMA GEMMs (fp32 accum).
// R5: 256x256-tile 8-phase-per-2-tiles schedule (T2+T3+T4+T5 port):
//   - 512 thr / 8 waves (2Mx4N), per-wave 128x64 C, acc[8][4]
//   - LDS 128KiB as K-slice planes [buf][ks][256 rows][32 elems]; stage units
//     (16KiB) are LDS-contiguous so global_load_lds width=16 applies; chunk
//     swizzle slot = q ^ ((row>>1)&3) folded into the GLOBAL source address
//     (both-sides rule), giving 2-way-only LDS bank aliasing on ds_read_b128.
//   - 4 phases/tile = (kslice, C-half): 16 MFMA + 4-8 ds_read_b128 + one
//     16KiB prefetch per phase; raw s_barrier pairs; lgkmcnt(0)+sched_barrier;
//     setprio(1) around MFMA; counted s_waitcnt vmcnt(8) twice per tile
//     (never 0 in the main loop - 2 units stay in flight across boundaries).
//   - stage schedule proven race-free: (t+1).ks1 staged at p0/p1 (other buf),
//     (t+2).ks0 staged at p2/p3 (same buf, region last read at p1/p0).
// ---------------------------------------------------------------------------

typedef __bf16 bf16x8 __attribute__((ext_vector_type(8)));
typedef float f32x4 __attribute__((ext_vector_type(4)));

__device__ __forceinline__ void gl_lds16(const void* g, void* l) {
  __builtin_amdgcn_global_load_lds((const __attribute__((address_space(1))) void*)g,
                                   (__attribute__((address_space(3))) void*)l, 16, 0, 0);
}

// ---------------- cast fp32 -> bf16, 8 elems/thread ----------------
__global__ __launch_bounds__(256) void cast_f32_bf16(const float* __restrict__ in,
                                                     __hip_bfloat16* __restrict__ out, int n) {
  int i = (blockIdx.x * 256 + threadIdx.x) * 8;
  if (i >= n) return;
  float4 a = *(const float4*)(in + i);
  float4 b = *(const float4*)(in + i + 4);
  __align__(16) __hip_bfloat16 o[8];
  o[0] = __float2bfloat16(a.x); o[1] = __float2bfloat16(a.y);
  o[2] = __float2bfloat16(a.z); o[3] = __float2bfloat16(a.w);
  o[4] = __float2bfloat16(b.x); o[5] = __float2bfloat16(b.y);
  o[6] = __float2bfloat16(b.z); o[7] = __float2bfloat16(b.w);
  *(uint4*)(out + i) = *(const uint4*)o;
}

// ============ shared GEMM core: 256x256 tile, BK=64, 8-phase schedule ======
// LDS plane bases (elems): A buf b plane ks -> (b*2+ks)*8192 ; B -> +32768.
// Stage one 16KiB unit (256 rows x 32 cols, one K-slice) of tile TT:
#define STAGE_(SRCP, OFFS, LDSBASE, TT, KS)                                        \
  if ((TT) < NT) {                                                                 \
    const int kb_ = (TT) * 64 + (KS) * 32;                                         \
    _Pragma("unroll") for (int i = 0; i < 2; ++i)                                  \
      gl_lds16((SRCP) + OFFS[i] + kb_,                                             \
               sm + (LDSBASE) + (size_t)(tid + 512 * i) * 8);                      \
  }

// One phase: (kslice plane APL/BPL, C-half CH). LOADB: refresh B frags.
// DOVM: counted vmcnt(8) before the closing barrier. __VA_ARGS__ = stage stmt.
#define PHASE_(APL, BPL, CH, LOADB, DOVM, ...)                                     \
  {                                                                                \
    const __hip_bfloat16* Ap_ = sm + (APL) * 8192;                                 \
    _Pragma("unroll") for (int mi = 0; mi < 4; ++mi)                               \
      af[mi] = *(const bf16x8*)(Ap_ + arow + ((CH) * 4 + mi) * 512);               \
    if (LOADB) {                                                                   \
      const __hip_bfloat16* Bp_ = sm + 32768 + (BPL) * 8192;                       \
      _Pragma("unroll") for (int ni = 0; ni < 4; ++ni)                             \
        bfr[ni] = *(const bf16x8*)(Bp_ + brow + ni * 512);                         \
    }                                                                              \
    __VA_ARGS__;                                                                   \
    __builtin_amdgcn_s_barrier();                                                  \
    asm volatile("s_waitcnt lgkmcnt(0)" ::: "memory");                             \
    __builtin_amdgcn_sched_barrier(0);                                             \
    __builtin_amdgcn_s_setprio(1);                                                 \
    _Pragma("unroll") for (int mi = 0; mi < 4; ++mi)                               \
      _Pragma("unroll") for (int ni = 0; ni < 4; ++ni)                             \
        acc[(CH) * 4 + mi][ni] = __builtin_amdgcn_mfma_f32_16x16x32_bf16(          \
            af[mi], bfr[ni], acc[(CH) * 4 + mi][ni], 0, 0, 0);                     \
    __builtin_amdgcn_s_setprio(0);                                                 \
    if (DOVM) asm volatile("s_waitcnt vmcnt(8)" ::: "memory");                     \
    __builtin_amdgcn_s_barrier();                                                  \
  }

// C = A @ B^T ; A:[M,K] bf16 lda, B:[N,K] bf16 ldb (row-major over K).
#define GEMM_CORE256(APTR, LDA, BPTR, LDB, KLEN)                                   \
  __shared__ __align__(16) __hip_bfloat16 sm[65536]; /* 128 KiB */                 \
  const __hip_bfloat16* Abase_ = (APTR);                                           \
  const __hip_bfloat16* Bbase_ = (BPTR);                                           \
  const int tid  = threadIdx.x;                                                    \
  const int lane = tid & 63;                                                       \
  const int q    = lane >> 4;                                                      \
  const int m16  = lane & 15;                                                      \
  const int wave = tid >> 6;                                                       \
  const int wr   = wave >> 2;                                                      \
  const int wc   = wave & 3;                                                       \
  const int row0 = blockIdx.y * 256;                                               \
  const int col0 = blockIdx.x * 256;                                               \
  /* staging: chunk c=tid+512*i of a unit: plane row r=c>>2, slot s=c&3 holds  */  \
  /* global k-chunk s ^ ((r>>1)&3)  (inverse-swizzled SOURCE, linear LDS dest) */  \
  unsigned srcA[2], srcB[2];                                                       \
  _Pragma("unroll") for (int i = 0; i < 2; ++i) {                                  \
    const int c_ = tid + 512 * i;                                                  \
    const int r_ = c_ >> 2;                                                        \
    const int kc_ = ((c_ & 3) ^ ((r_ >> 1) & 3)) * 8;                              \
    srcA[i] = (unsigned)(row0 + r_) * (unsigned)(LDA) + (unsigned)kc_;             \
    srcB[i] = (unsigned)(col0 + r_) * (unsigned)(LDB) + (unsigned)kc_;             \
  }                                                                                \
  const int NT = (KLEN) >> 6;                                                      \
  f32x4 acc[8][4];                                                                 \
  { const f32x4 z_ = {0.f, 0.f, 0.f, 0.f};                                         \
    _Pragma("unroll") for (int i = 0; i < 8; ++i)                                  \
      _Pragma("unroll") for (int j = 0; j < 4; ++j) acc[i][j] = z_; }              \
  /* ds_read swizzle (matches source swizzle): slot = q ^ ((row>>1)&3) */          \
  const int soff = (q ^ ((m16 >> 1) & 3)) * 8;                                     \
  const int arow = (wr * 128 + m16) * 32 + soff;                                   \
  const int brow = (wc * 64 + m16) * 32 + soff;                                    \
  bf16x8 af[4], bfr[4];                                                            \
  /* prologue: t0.{A0,B0,A1,B1} + t1.{A0,B0}; keep youngest 4 loads in flight */   \
  STAGE_(Abase_, srcA, 0,             0, 0)                                        \
  STAGE_(Bbase_, srcB, 32768 + 0,     0, 0)                                        \
  STAGE_(Abase_, srcA, 8192,          0, 1)                                        \
  STAGE_(Bbase_, srcB, 32768 + 8192,  0, 1)                                        \
  STAGE_(Abase_, srcA, 16384,         1, 0)                                        \
  STAGE_(Bbase_, srcB, 32768 + 16384, 1, 0)                                        \
  asm volatile("s_waitcnt vmcnt(8)" ::: "memory");                                 \
  __builtin_amdgcn_s_barrier();                                                    \
  for (int t = 0; t < NT; t += 2) {                                                \
    /* tile t (buf0, planes A:0/1 B:0/1) */                                        \
    PHASE_(0, 0, 0, 1, 0, STAGE_(Abase_, srcA, 24576,         t + 1, 1))           \
    PHASE_(0, 0, 1, 0, 1, STAGE_(Bbase_, srcB, 32768 + 24576, t + 1, 1))           \
    PHASE_(1, 1, 0, 1, 0, STAGE_(Abase_, srcA, 0,             t + 2, 0))           \
    PHASE_(1, 1, 1, 0, 1, STAGE_(Bbase_, srcB, 32768 + 0,     t + 2, 0))           \
    /* tile t+1 (buf1, planes A:2/3 B:2/3) */                                      \
    PHASE_(2, 2, 0, 1, 0, STAGE_(Abase_, srcA, 8192,          t + 2, 1))           \
    PHASE_(2, 2, 1, 0, 1, STAGE_(Bbase_, srcB, 32768 + 8192,  t + 2, 1))           \
    PHASE_(3, 3, 0, 1, 0, STAGE_(Abase_, srcA, 16384,         t + 3, 0))           \
    PHASE_(3, 3, 1, 0, 1, STAGE_(Bbase_, srcB, 32768 + 16384, t + 3, 0))           \
  }                                                                                \
  /* C/D layout (m89/m91): col = lane&15, row = (lane>>4)*4 + reg */               \
  const int crow = row0 + wr * 128 + q * 4;                                        \
  const int ccol = col0 + wc * 64 + m16;

// ---------------- batched gemm ----------------
// OUT_MODE: 0 = bf16 out; 2 = f32 out * (1/rsum[row]) + bias[col]
template<int OUT_MODE>
__global__ __launch_bounds__(512) void gemm_bt(
    const __hip_bfloat16* __restrict__ A, int lda, long long sA,
    const __hip_bfloat16* __restrict__ B, int ldb, long long sB,
    void* __restrict__ Cv, int ldc, long long sC,
    const float* __restrict__ bias, const float* __restrict__ rsum, int K)
{
  const int bz = blockIdx.z;
  GEMM_CORE256(A + (size_t)bz * sA, lda, B + (size_t)bz * sB, ldb, K)
  if constexpr (OUT_MODE == 0) {
    __hip_bfloat16* C = (__hip_bfloat16*)Cv + (size_t)bz * sC;
    #pragma unroll
    for (int mi = 0; mi < 8; ++mi)
      #pragma unroll
      for (int ni = 0; ni < 4; ++ni)
        #pragma unroll
        for (int r = 0; r < 4; ++r)
          C[(size_t)(crow + mi * 16 + r) * ldc + ccol + ni * 16] = __float2bfloat16(acc[mi][ni][r]);
  } else {
    float* C = (float*)Cv + (size_t)bz * sC;
    float bv[4];
    #pragma unroll
    for (int ni = 0; ni < 4; ++ni) bv[ni] = bias[ccol + ni * 16];
    #pragma unroll
    for (int mi = 0; mi < 8; ++mi) {
      float sc[4];
      #pragma unroll
      for (int r = 0; r < 4; ++r) sc[r] = 1.f / rsum[crow + mi * 16 + r];
      #pragma unroll
      for (int ni = 0; ni < 4; ++ni)
        #pragma unroll
        for (int r = 0; r < 4; ++r)
          C[(size_t)(crow + mi * 16 + r) * ldc + ccol + ni * 16] =
              acc[mi][ni][r] * sc[r] + bv[ni];
    }
  }
}

// ---------------- QK^T gemm, fused exp epilogue + atomic row sums ----------------
// P' = exp(acc*0.125) (bf16); Lsum[row] += rowsum of the bf16-rounded P' tile.
__global__ __launch_bounds__(512) void gemm_qk_exp(
    const __hip_bfloat16* __restrict__ A, int lda, long long sA,
    const __hip_bfloat16* __restrict__ B, int ldb, long long sB,
    __hip_bfloat16* __restrict__ Pv, int ldc, long long sC,
    float* __restrict__ Lsum, int ldl, int K)
{
  const int bz = blockIdx.z;
  GEMM_CORE256(A + (size_t)bz * sA, lda, B + (size_t)bz * sB, ldb, K)
  __hip_bfloat16* C = Pv + (size_t)bz * sC;
  float* Lrow = Lsum + (size_t)bz * ldl;
  #pragma unroll
  for (int mi = 0; mi < 8; ++mi) {
    #pragma unroll
    for (int r = 0; r < 4; ++r) {
      float s = 0.f;
      #pragma unroll
      for (int ni = 0; ni < 4; ++ni) {
        const float e = __expf(acc[mi][ni][r] * 0.125f);
        const __hip_bfloat16 h = __float2bfloat16(e);
        C[(size_t)(crow + mi * 16 + r) * ldc + ccol + ni * 16] = h;
        s += __bfloat162float(h);
      }
      // reduce across the 16 lanes of this q-group (cols), then 1 atomic/row/wave
      #pragma unroll
      for (int mask = 1; mask < 16; mask <<= 1) s += __shfl_xor(s, mask);
      if (m16 == 0) atomicAdd(&Lrow[crow + mi * 16 + r], s);
    }
  }
}

// ---------------- QKV gemm with split epilogue ----------------
// Cols 0..2047 (Q,K) -> QK [M, 2048] bf16. Cols 2048..3071 (V) -> Vt [1024, M]
// (transposed). Branch is block-uniform (blockIdx.x < 8 => Q/K, >= 8 => V).
__global__ __launch_bounds__(512) void gemm_qkv(
    const __hip_bfloat16* __restrict__ A, int lda,
    const __hip_bfloat16* __restrict__ B, int ldb,
    __hip_bfloat16* __restrict__ QK,
    __hip_bfloat16* __restrict__ Vt, int M, int K)
{
  GEMM_CORE256(A, lda, B, ldb, K)
  if (blockIdx.x < 8) {
    #pragma unroll
    for (int mi = 0; mi < 8; ++mi)
      #pragma unroll
      for (int ni = 0; ni < 4; ++ni)
        #pragma unroll
        for (int r = 0; r < 4; ++r)
          QK[(size_t)(crow + mi * 16 + r) * 2048 + ccol + ni * 16] = __float2bfloat16(acc[mi][ni][r]);
  } else {
    #pragma unroll
    for (int mi = 0; mi < 8; ++mi) {
      const int rowbase = crow + mi * 16;  // multiple of 4 -> 8B-aligned dest
      #pragma unroll
      for (int ni = 0; ni < 4; ++ni) {
        const int vc = ccol + ni * 16 - 2048;
        __align__(8) __hip_bfloat16 o[4];
        #pragma unroll
        for (int r = 0; r < 4; ++r) o[r] = __float2bfloat16(acc[mi][ni][r]);
        *(uint2*)(Vt + (size_t)vc * M + rowbase) = *(const uint2*)o;
      }
    }
  }
}

// ---------------------------------------------------------------------------
extern "C" void kernel_launch(void* const* d_in, const int* in_sizes, int n_in,
                              void* d_out, int out_size, void* d_ws, size_t ws_size,
                              hipStream_t stream) {
  const float* x     = (const float*)d_in[0];   // [8, 2048, 1024]
  const float* w_qkv = (const float*)d_in[1];   // [3072, 1024]
  const float* w_out = (const float*)d_in[2];   // [1024, 1024]
  const float* b_out = (const float*)d_in[3];   // [1024]
  float* out = (float*)d_out;

  constexpr int Bz = 8, N = 2048, D = 1024, E = 3 * D;
  constexpr int M = Bz * N;  // 16384

  // ---- workspace: fixed regions + one dynamic region (aliased) ----
  // fixed: Wo(2.1) + Vt(33.5) + QK(67.1) + AO(33.5) + L(64K) ~ 136.3 MB
  // dynamic: phase1 Xb(33.5)+Wq(6.3)=39.8 ; phases 2-4 P'(G*8.4)
  char* p = (char*)d_ws;
  __hip_bfloat16* Wo = (__hip_bfloat16*)p; p += (size_t)D * D * 2;
  __hip_bfloat16* Vt = (__hip_bfloat16*)p; p += (size_t)D * M * 2;
  __hip_bfloat16* QK = (__hip_bfloat16*)p; p += (size_t)M * 2 * D * 2;
  __hip_bfloat16* AO = (__hip_bfloat16*)p; p += (size_t)M * D * 2;
  float*          L  = (float*)p;          p += (size_t)M * 4;
  char* dyn = p;
  const size_t fixed_sz = (size_t)(dyn - (char*)d_ws);
  const size_t xw_sz = (size_t)M * D * 2 + (size_t)E * D * 2;  // Xb + Wq

  int G = 1;
  for (int g = 8; g >= 1; g >>= 1) {
    size_t dyn_sz = (size_t)g * N * N * 2;  // P' bf16
    if (dyn_sz < xw_sz) dyn_sz = xw_sz;
    if (fixed_sz + dyn_sz <= ws_size) { G = g; break; }
  }

  __hip_bfloat16* Xb = (__hip_bfloat16*)dyn;
  __hip_bfloat16* Wq = (__hip_bfloat16*)(dyn + (size_t)M * D * 2);
  __hip_bfloat16* P  = (__hip_bfloat16*)dyn;

  // phase 1: casts + QKV projection (+ zero the row-sum accumulator)
  hipMemsetAsync(L, 0, (size_t)M * 4, stream);
  cast_f32_bf16<<<(M * D) / (8 * 256), 256, 0, stream>>>(x, Xb, M * D);
  cast_f32_bf16<<<(E * D) / (8 * 256), 256, 0, stream>>>(w_qkv, Wq, E * D);
  cast_f32_bf16<<<(D * D) / (8 * 256), 256, 0, stream>>>(w_out, Wo, D * D);
  gemm_qkv<<<dim3(E / 256, M / 256), 512, 0, stream>>>(Xb, D, Wq, D, QK, Vt, M, D);

  // phases 2-3: batched attention, groups of G
  for (int g = 0; g < Bz / G; ++g) {
    const __hip_bfloat16* Qg = QK + (size_t)g * G * N * (2 * D);
    // P' = exp(Q @ K^T * 0.125) (bf16) + atomic row sums into L
    gemm_qk_exp<<<dim3(N / 256, N / 256, G), 512, 0, stream>>>(
        Qg, 2 * D, (long long)N * 2 * D,
        Qg + D, 2 * D, (long long)N * 2 * D,
        P, N, (long long)N * N,
        L + (size_t)g * G * N, N, D);
    // O' = P' @ Vt^T (bf16, unnormalized)
    gemm_bt<0><<<dim3(D / 256, N / 256, G), 512, 0, stream>>>(
        P, N, (long long)N * N,
        Vt + (size_t)g * G * N, M, (long long)N,
        AO + (size_t)g * G * N * D, D, (long long)N * D,
        nullptr, nullptr, N);
  }

  // phase 4: y = (O' @ Wout^T) / l[row] + b
  gemm_bt<2><<<dim3(D / 256, M / 256, 1), 512, 0, stream>>>(
      AO, D, 0LL, Wo, D, 0LL, out, D, 0LL, b_out, L, D);
}